// Round 6
// baseline (232.254 us; speedup 1.0000x reference)
//
#include <hip/hip_runtime.h>
#include <hip/hip_bf16.h>

// R11: isolate the R9/R10 numerics bug.
// R10 post-mortem: cvt_pk revert only moved 1.72e-2 -> 1.19e-2, so the
// dominant bug is in what R9/R10 share vs R8(pass): permlane32_swap (whose
// correctness rested on an UNVERIFIED half-swap convention), the 1-barrier
// dbuf (race argument re-derived, solid), or max-nesting (bit-exact).
// -> revert ONLY the exchanges to R8-verified __shfl_xor(.,32); KEEP the
// single-barrier K/V double-buffer. Clean A/B: pass => permlane was it.

#define B_ 2
#define S_ 2048
#define D_ 1024
#define H_ 16
#define HD_ 64
#define NE_ (B_ * S_ * D_)  // 4194304
#define WN_ (D_ * D_)       // 1048576

typedef unsigned short u16;
typedef unsigned int u32;
typedef u16 __attribute__((may_alias)) u16_ma;
typedef float __attribute__((may_alias)) f32_ma;
typedef u32 v4u __attribute__((ext_vector_type(4)));
typedef v4u __attribute__((may_alias)) v4u_ma;
typedef short bf16x8 __attribute__((ext_vector_type(8)));
typedef bf16x8 __attribute__((may_alias)) bf16x8_ma;
typedef float f32x4 __attribute__((ext_vector_type(4)));
typedef float f32x16 __attribute__((ext_vector_type(16)));

__device__ __forceinline__ float bf2f(u16 u) {
  u32 x = ((u32)u) << 16;
  return __builtin_bit_cast(float, x);
}
// Software RNE f32->bf16 (harness-verified numerics, R5-R8).
__device__ __forceinline__ u16 f2bf(float f) {
  __hip_bfloat16 h = __float2bfloat16(f);
  return __builtin_bit_cast(u16, h);
}
__device__ __forceinline__ u32 pk2(u32 alo, u32 ahi) {
  return (u32)f2bf(__builtin_bit_cast(float, alo)) |
         ((u32)f2bf(__builtin_bit_cast(float, ahi)) << 16);
}
__device__ __forceinline__ u32 pkf(float lo, float hi) {
  return (u32)f2bf(lo) | ((u32)f2bf(hi) << 16);
}

// async global->LDS, 16B/lane; dest = wave-uniform base + lane*16 (m104).
__device__ __forceinline__ void gl_lds16(const u16* g, u16* l) {
  auto gp = (const __attribute__((address_space(1))) unsigned int*)(const void*)g;
  auto lp = (__attribute__((address_space(3))) unsigned int*)(void*)l;
  __builtin_amdgcn_global_load_lds(gp, lp, 16, 0, 0);
}

// Input dtype detect (R5-R8 harness-verified).
__device__ __forceinline__ bool detect_f32(const u16* Wg) {
  const int lane = threadIdx.x & 63;
  bool hit = false;
#pragma unroll
  for (int i = 0; i < 4; ++i) {
    v4u u = *(const v4u_ma*)(Wg + lane * 32 + i * 8);
#pragma unroll
    for (int j = 0; j < 4; ++j) {
      u32 w = u[j];
      hit |= (((w >> 7) & 0xFFu) >= 0xF0u) || (((w >> 23) & 0xFFu) >= 0xF0u);
    }
  }
  return __any(hit);
}

// ---------------------------------------------------------------------------
// Convert all 7 input buffers to bf16 scratch (copy if already bf16).
// ---------------------------------------------------------------------------
__global__ __launch_bounds__(256) void convert_bf16(
    const void* s0, const void* s1, const void* s2, const void* s3,
    const void* s4, const void* s5, const void* s6, u16* __restrict__ dst_in,
    u16* __restrict__ dst_w, const u16* __restrict__ Wdet) {
  const bool det = detect_f32(Wdet);
  const int y = blockIdx.y;
  const void* src;
  u16* dst;
  int n;
  if (y < 3) {
    src = (y == 0) ? s0 : ((y == 1) ? s1 : s2);
    dst = dst_in + (size_t)y * NE_;
    n = NE_;
  } else {
    src = (y == 3) ? s3 : ((y == 4) ? s4 : ((y == 5) ? s5 : s6));
    dst = dst_w + (size_t)(y - 3) * WN_;
    n = WN_;
  }
  const int i = (blockIdx.x * 256 + threadIdx.x) * 8;
  if (i >= n) return;
  v4u out;
  if (det) {
    const v4u_ma* fp = (const v4u_ma*)((const float*)src + i);
    v4u f0 = fp[0], f1 = fp[1];
    out[0] = pk2(f0[0], f0[1]);
    out[1] = pk2(f0[2], f0[3]);
    out[2] = pk2(f1[0], f1[1]);
    out[3] = pk2(f1[2], f1[3]);
  } else {
    out = *(const v4u_ma*)((const u16*)src + i);
  }
  *(v4u_ma*)(dst + i) = out;
}

// ---------------------------------------------------------------------------
// C[4096,1024] = A @ W^T, all-bf16. BM=128, BK=64, BN templated.
// XOR-swizzled LDS rows (128B) via pre-swizzled gl_lds SOURCE (rule #21).
// blockIdx.z fuses QKV. z==0 folds exact 1/sqrt(HD)=0.125 into Q.
// (R8-verified, unchanged.)
// ---------------------------------------------------------------------------
template <int BN, bool OUT_DET>
__global__ __launch_bounds__(256) void proj_g(
    const u16* __restrict__ Ab, const u16* __restrict__ Wb,
    void* __restrict__ Cb, const u16* __restrict__ Wdet) {
  __shared__ u16 Al[128 * 64];
  __shared__ u16 Wl[BN * 64];

  const bool outf32 = OUT_DET ? detect_f32(Wdet) : false;

  const int tid = threadIdx.x;
  const int lane = tid & 63, wid = tid >> 6;
  const int lg = lane >> 4, li = lane & 15;
  const int wr = wid >> 1, wc = wid & 1;
  const int z = blockIdx.z;
  const char* Ag = (const char*)(Ab + (size_t)z * NE_);
  const char* Wg = (const char*)(Wb + (size_t)z * WN_);
  const int m0 = blockIdx.x * 128, n0 = blockIdx.y * BN;

  const int lr = lane >> 3;
  const int swzb = ((lane & 7) * 16) ^ (lr << 4);

  constexpr int NF = BN / 32;
  f32x4 acc[4][NF];
#pragma unroll
  for (int m = 0; m < 4; ++m)
#pragma unroll
    for (int n = 0; n < NF; ++n) acc[m][n] = (f32x4){0.f, 0.f, 0.f, 0.f};

  for (int kt = 0; kt < 16; ++kt) {
    const int k0b = kt * 128;  // byte offset along K (64 elems)
    __syncthreads();
#pragma unroll
    for (int c = 0; c < 4; ++c) {
      const int row = wid * 32 + c * 8 + lr;
      gl_lds16((const u16*)(Ag + (size_t)(m0 + row) * 2048 + k0b + swzb),
               Al + (wid * 32 + c * 8) * 64);
    }
    if constexpr (BN == 128) {
#pragma unroll
      for (int c = 0; c < 4; ++c) {
        const int row = wid * 32 + c * 8 + lr;
        gl_lds16((const u16*)(Wg + (size_t)(n0 + row) * 2048 + k0b + swzb),
                 Wl + (wid * 32 + c * 8) * 64);
      }
    } else {
#pragma unroll
      for (int c = 0; c < 2; ++c) {
        const int row = wid * 16 + c * 8 + lr;
        gl_lds16((const u16*)(Wg + (size_t)(n0 + row) * 2048 + k0b + swzb),
                 Wl + (wid * 16 + c * 8) * 64);
      }
    }
    __syncthreads();

#pragma unroll
    for (int ks = 0; ks < 2; ++ks) {
      bf16x8 af[4], bw[NF];
#pragma unroll
      for (int m = 0; m < 4; ++m) {
        const int row = wr * 64 + m * 16 + li;
        af[m] = *(const bf16x8_ma*)((const char*)Al + row * 128 +
                                    ((ks * 64 + lg * 16) ^ ((row & 7) << 4)));
      }
#pragma unroll
      for (int n = 0; n < NF; ++n) {
        const int row = wc * (BN / 2) + n * 16 + li;
        bw[n] = *(const bf16x8_ma*)((const char*)Wl + row * 128 +
                                    ((ks * 64 + lg * 16) ^ ((row & 7) << 4)));
      }
#pragma unroll
      for (int m = 0; m < 4; ++m)
#pragma unroll
        for (int n = 0; n < NF; ++n)
          acc[m][n] = __builtin_amdgcn_mfma_f32_16x16x32_bf16(af[m], bw[n],
                                                              acc[m][n], 0, 0, 0);
    }
  }

  // Q (z==0) carries exact 1/sqrt(64) = 0.125 (power of two, no extra error).
  const float zs = (!OUT_DET && z == 0) ? 0.125f : 1.0f;
#pragma unroll
  for (int m = 0; m < 4; ++m)
#pragma unroll
    for (int n = 0; n < NF; ++n)
#pragma unroll
      for (int r = 0; r < 4; ++r) {
        const int row = m0 + wr * 64 + m * 16 + lg * 4 + r;
        const int col = n0 + wc * (BN / 2) + n * 16 + li;
        const size_t idx = (size_t)row * D_ + col;
        const float v = acc[m][n][r] * zs;
        if (OUT_DET) {
          if (outf32)
            ((f32_ma*)Cb)[idx] = v;
          else
            ((u16_ma*)Cb)[idx] = f2bf(v);
        } else {
          ((u16_ma*)((u16*)Cb + (size_t)z * NE_))[idx] = f2bf(v);
        }
      }
}

// ---------------------------------------------------------------------------
// Flash attention: 32x32x16 MFMA swapped operands (R8-verified layout+math),
// __shfl_xor(.,32) exchanges (R8-verified), K/V LDS double-buffer with ONE
// barrier per 64-key tile (race-analysis-clean). Softmax nats + __expf.
// ---------------------------------------------------------------------------
__global__ __launch_bounds__(256) void attn3(
    const u16* __restrict__ Qg, const u16* __restrict__ Kg,
    const u16* __restrict__ Vg, u16* __restrict__ Og) {
  __shared__ u16 Kl[2][64 * 64];
  __shared__ u16 VTl[2][64 * 64];

  const int tid = threadIdx.x;
  const int wid = tid >> 6, lane = tid & 63;
  const int l31 = lane & 31;
  const int hi = lane >> 5;

  // T1 XCD swizzle (512 % 8 == 0)
  const int bid = blockIdx.x;
  const int swz = (bid & 7) * 64 + (bid >> 3);
  const int qb = swz & 15;
  const int h = (swz >> 4) & 15;
  const int b = swz >> 8;
  const size_t bbase = (size_t)b * S_ * D_;
  const int hoff = h * HD_;
  const int q0w = qb * 128 + wid * 32;

  // Q B-frags: bq[dblk] -> Q[q0w+l31][hoff + dblk*16 + hi*8 + e]
  bf16x8 bq[4];
  {
    const u16* qp = Qg + bbase + (size_t)(q0w + l31) * D_ + hoff + hi * 8;
#pragma unroll
    for (int dblk = 0; dblk < 4; ++dblk)
      bq[dblk] = *(const bf16x8_ma*)(qp + dblk * 16);
  }

  f32x16 o0, o1;
#pragma unroll
  for (int i = 0; i < 16; ++i) {
    o0[i] = 0.f;
    o1[i] = 0.f;
  }
  float mrun = -1e30f, lrun = 0.f;

  const int krr = tid >> 3;
  const int kc8 = (tid & 7) * 8;
  const int vkr = lane;
  const int vd0 = wid * 8;

  v4u kr0, kr1, vr0, vr1;
  auto kv_load = [&](int kt) {
    const int key0 = kt * 64;
    kr0 = *(const v4u_ma*)(Kg + bbase + (size_t)(key0 + krr) * D_ + hoff + kc8);
    kr1 = *(const v4u_ma*)(Kg + bbase + (size_t)(key0 + 32 + krr) * D_ + hoff + kc8);
    vr0 = *(const v4u_ma*)(Vg + bbase + (size_t)(key0 + vkr) * D_ + hoff + vd0);
    vr1 = *(const v4u_ma*)(Vg + bbase + (size_t)(key0 + vkr) * D_ + hoff + vd0 + 32);
  };
  auto kv_write = [&](int bi) {
    char* Kb = (char*)&Kl[bi][0];
    char* Vb = (char*)&VTl[bi][0];
    const int ksw = (krr & 7) << 4;
    *(v4u_ma*)(Kb + krr * 128 + ((kc8 * 2) ^ ksw)) = kr0;
    *(v4u_ma*)(Kb + (32 + krr) * 128 + ((kc8 * 2) ^ ksw)) = kr1;
    union {
      v4u v;
      u16 e[8];
    } uu;
    uu.v = vr0;
#pragma unroll
    for (int j = 0; j < 8; ++j) {
      const int d = vd0 + j;
      *(u16*)(Vb + d * 128 + ((vkr * 2) ^ ((d & 7) << 4))) = uu.e[j];
    }
    uu.v = vr1;
#pragma unroll
    for (int j = 0; j < 8; ++j) {
      const int d = vd0 + 32 + j;
      *(u16*)(Vb + d * 128 + ((vkr * 2) ^ ((d & 7) << 4))) = uu.e[j];
    }
  };

  kv_load(0);
  kv_write(0);

  const int swk = (l31 & 7) << 4;

  for (int kt = 0; kt < S_ / 64; ++kt) {
    __syncthreads();  // buf[kt&1] writes visible; prior-iter reads all done
    if (kt < S_ / 64 - 1) kv_load(kt + 1);  // in flight across compute

    const char* Kb = (const char*)&Kl[kt & 1][0];
    const char* Vb = (const char*)&VTl[kt & 1][0];

    // QK^T (Q pre-scaled by exact 0.125)
    f32x16 sT0, sT1;
#pragma unroll
    for (int i = 0; i < 16; ++i) {
      sT0[i] = 0.f;
      sT1[i] = 0.f;
    }
    __builtin_amdgcn_s_setprio(1);
#pragma unroll
    for (int dblk = 0; dblk < 4; ++dblk) {
      const int cb = (dblk * 32 + hi * 16);
      bf16x8 a0 = *(const bf16x8_ma*)(Kb + l31 * 128 + (cb ^ swk));
      bf16x8 a1 = *(const bf16x8_ma*)(Kb + (32 + l31) * 128 + (cb ^ swk));
      sT0 = __builtin_amdgcn_mfma_f32_32x32x16_bf16(a0, bq[dblk], sT0, 0, 0, 0);
      sT1 = __builtin_amdgcn_mfma_f32_32x32x16_bf16(a1, bq[dblk], sT1, 0, 0, 0);
    }
    __builtin_amdgcn_s_setprio(0);

    // row max (exact, order-free), cross-half via R8-verified shfl
    float pmax = sT0[0];
#pragma unroll
    for (int i = 0; i < 7; ++i)
      pmax = fmaxf(fmaxf(pmax, sT0[2 * i + 1]), sT0[2 * i + 2]);
    pmax = fmaxf(pmax, sT0[15]);
#pragma unroll
    for (int i = 0; i < 8; ++i)
      pmax = fmaxf(fmaxf(pmax, sT1[2 * i]), sT1[2 * i + 1]);
    pmax = fmaxf(pmax, __shfl_xor(pmax, 32));
    // T13 defer-max (nats, thr 8: P bounded by e^8, R8-verified)
    if (!__all(pmax - mrun <= 8.0f)) {
      const float mnew = fmaxf(mrun, pmax);
      const float al = __expf(mrun - mnew);
      mrun = mnew;
      lrun *= al;
      o0 *= al;
      o1 *= al;
    }

    // p = exp(s - m); software RNE pack (R8-verified numerics)
    u32 w[16];
    float sum = 0.f;
#pragma unroll
    for (int kh = 0; kh < 2; ++kh)
#pragma unroll
      for (int g = 0; g < 4; ++g)
#pragma unroll
        for (int u = 0; u < 2; ++u) {
          const int r = g * 4 + 2 * u;
          const float pe = __expf((kh ? sT1[r] : sT0[r]) - mrun);
          const float po = __expf((kh ? sT1[r + 1] : sT0[r + 1]) - mrun);
          sum += pe + po;
          w[kh * 8 + g * 2 + u] = pkf(pe, po);
        }
    sum += __shfl_xor(sum, 32);
    lrun += sum;

    // P B-frags via R8-VERIFIED shfl pair exchange
    bf16x8 pf[4];
#pragma unroll
    for (int km = 0; km < 4; ++km) {
      const int a = 4 * km;
      const u32 s0 = hi ? w[a] : w[a + 2];
      const u32 s1 = hi ? w[a + 1] : w[a + 3];
      const u32 r0 = (u32)__shfl_xor((int)s0, 32);
      const u32 r1 = (u32)__shfl_xor((int)s1, 32);
      union {
        u32 d[4];
        bf16x8 v;
      } uu;
      uu.d[0] = hi ? r0 : w[a];
      uu.d[1] = hi ? r1 : w[a + 1];
      uu.d[2] = hi ? w[a + 2] : r0;
      uu.d[3] = hi ? w[a + 3] : r1;
      pf[km] = uu.v;
    }

    // PV: O^T += V^T P^T
    __builtin_amdgcn_s_setprio(1);
#pragma unroll
    for (int km = 0; km < 4; ++km) {
      const int cb = (km * 32 + hi * 16);
      bf16x8 v0 = *(const bf16x8_ma*)(Vb + l31 * 128 + (cb ^ swk));
      bf16x8 v1 = *(const bf16x8_ma*)(Vb + (32 + l31) * 128 + (cb ^ swk));
      o0 = __builtin_amdgcn_mfma_f32_32x32x16_bf16(v0, pf[km], o0, 0, 0, 0);
      o1 = __builtin_amdgcn_mfma_f32_32x32x16_bf16(v1, pf[km], o1, 0, 0, 0);
    }
    __builtin_amdgcn_s_setprio(0);

    if (kt < S_ / 64 - 1) kv_write((kt + 1) & 1);
  }

  // epilogue: lane holds O[q=q0w+l31][d=(r&3)+8*(r>>2)+4*hi (+32)]
  const float inv = 1.f / lrun;
  u16* orow = Og + bbase + (size_t)(q0w + l31) * D_ + hoff;
#pragma unroll
  for (int r = 0; r < 16; ++r) {
    const int d0 = (r & 3) + 8 * (r >> 2) + 4 * hi;
    orow[d0] = f2bf(o0[r] * inv);
    orow[d0 + 32] = f2bf(o1[r] * inv);
  }
}

// ---------------------------------------------------------------------------
// R5 golden slow path — fallback for small-ws worlds.
// ---------------------------------------------------------------------------
template <bool A_SCR, bool SCR_F32, bool OUT_FINAL>
__global__ __launch_bounds__(256) void proj_slow(
    const void* __restrict__ Ag, const u16* __restrict__ Wg,
    void* __restrict__ Cg) {
  const bool det = detect_f32(Wg);
  const bool a_f32 = A_SCR ? SCR_F32 : det;
  const int m = blockIdx.x;
  const int n = blockIdx.y * 256 + threadIdx.x;
  const size_t arow = (size_t)m * D_;
  const size_t wrow = (size_t)n * D_;
  float acc = 0.f;
  for (int k = 0; k < D_; ++k) {
    float a = a_f32 ? ((const f32_ma*)Ag)[arow + k]
                    : bf2f(((const u16_ma*)Ag)[arow + k]);
    float w = det ? ((const f32_ma*)Wg)[wrow + k]
                  : bf2f(((const u16_ma*)Wg)[wrow + k]);
    acc += a * w;
  }
  const size_t ci = (size_t)m * D_ + n;
  const bool c_f32 = OUT_FINAL ? det : SCR_F32;
  if (c_f32)
    ((f32_ma*)Cg)[ci] = acc;
  else
    ((u16_ma*)Cg)[ci] = f2bf(acc);
}

template <bool SCR_F32>
__global__ __launch_bounds__(256) void attn_slow(
    const void* __restrict__ Qg, const void* __restrict__ Kg,
    const void* __restrict__ Vg, void* __restrict__ Cg) {
  const int tid = threadIdx.x;
  const int qblk = blockIdx.x & 7;
  const int h = (blockIdx.x >> 3) & 15;
  const int b = blockIdx.x >> 7;
  const int q = qblk * 256 + tid;
  const size_t base = (size_t)b * S_ * D_;
  const int hoff = h * HD_;
  float qv[64];
  {
    const size_t qrow = base + (size_t)q * D_ + hoff;
    for (int d = 0; d < 64; ++d)
      qv[d] = SCR_F32 ? ((const f32_ma*)Qg)[qrow + d]
                      : bf2f(((const u16_ma*)Qg)[qrow + d]);
  }
  float o[64];
  for (int d = 0; d < 64; ++d) o[d] = 0.f;
  float m = -1e30f, l = 0.f;
  for (int key = 0; key < S_; ++key) {
    const size_t krow = base + (size_t)key * D_ + hoff;
    float s = 0.f;
    for (int d = 0; d < 64; ++d) {
      float kx = SCR_F32 ? ((const f32_ma*)Kg)[krow + d]
                         : bf2f(((const u16_ma*)Kg)[krow + d]);
      s += qv[d] * kx;
    }
    s *= 0.125f;
    float mn = fmaxf(m, s);
    float al = expf(m - mn);
    float pe = expf(s - mn);
    m = mn;
    l = l * al + pe;
    for (int d = 0; d < 64; ++d) {
      float vx = SCR_F32 ? ((const f32_ma*)Vg)[krow + d]
                         : bf2f(((const u16_ma*)Vg)[krow + d]);
      o[d] = o[d] * al + pe * vx;
    }
  }
  const float il = 1.f / l;
  const size_t crow = base + (size_t)q * D_ + hoff;
  for (int d = 0; d < 64; ++d) {
    if (SCR_F32)
      ((f32_ma*)Cg)[crow + d] = o[d] * il;
    else
      ((u16_ma*)Cg)[crow + d] = f2bf(o[d] * il);
  }
}

extern "C" void kernel_launch(void* const* d_in, const int* in_sizes, int n_in,
                              void* d_out, int out_size, void* d_ws,
                              size_t ws_size, hipStream_t stream) {
  const u16* Wdet = (const u16*)d_in[3];  // pristine Wq for dtype detect
  dim3 blk(256);

  if (ws_size >= (size_t)4 * NE_ * sizeof(float)) {
    u16* Qi = (u16*)d_ws;
    u16* Wc = Qi + (size_t)3 * NE_;
    u16* Qp = Wc + (size_t)4 * WN_;
    u16* Xp = Qp + (size_t)3 * NE_;

    convert_bf16<<<dim3(2048, 7), blk, 0, stream>>>(
        d_in[0], d_in[1], d_in[2], d_in[3], d_in[4], d_in[5], d_in[6], Qi, Wc,
        Wdet);
    proj_g<128, false><<<dim3(32, 8, 3), blk, 0, stream>>>(Qi, Wc, Qp, Wdet);
    attn3<<<dim3(512), blk, 0, stream>>>(Qp, Qp + NE_, Qp + (size_t)2 * NE_, Xp);
    proj_g<64, true><<<dim3(32, 16, 1), blk, 0, stream>>>(
        Xp, Wc + (size_t)3 * WN_, d_out, Wdet);
  } else {
    dim3 gproj(B_ * S_, D_ / 256);
    dim3 gattn(B_ * H_ * (S_ / 256));
    u16* Qp = (u16*)d_out;
    u16* Kp = (u16*)d_in[0];
    u16* Vp = (u16*)d_in[1];
    u16* Xp = (u16*)d_in[2];
    proj_slow<false, false, false><<<gproj, blk, 0, stream>>>(
        d_in[0], (const u16*)d_in[3], Qp);
    proj_slow<false, false, false><<<gproj, blk, 0, stream>>>(
        d_in[1], (const u16*)d_in[4], Kp);
    proj_slow<false, false, false><<<gproj, blk, 0, stream>>>(
        d_in[2], (const u16*)d_in[5], Vp);
    attn_slow<false><<<gattn, blk, 0, stream>>>(Qp, Kp, Vp, Xp);
    proj_slow<true, false, true><<<gproj, blk, 0, stream>>>(
        Xp, (const u16*)d_in[6], d_out);
  }
}

// Round 7
// 231.127 us; speedup vs baseline: 1.0049x; 1.0049x over previous
//
#include <hip/hip_runtime.h>
#include <hip/hip_bf16.h>

// R12: kill the dead work + counted-vmcnt proj pipeline.
//  - convert: early-exit in bf16 world (pure copy was ~14us of the timed path);
//    proj selects source = original d_in (bf16 world) vs converted scratch
//    (fp32 world) via the verified detect.
//  - proj_g: LDS double-buffer + s_waitcnt vmcnt(8/6) counted waits (T4) --
//    loads stay in flight across barriers; no vmcnt(0) drain mid-loop.
//    (Same schedule class as attn3's verified single-barrier dbuf.)
//  - attn3: P-pack + epilogue use raw 3-op RNE (bit-identical to f2bf on
//    non-NaN inputs; P/O are exp/dot outputs, never NaN).
// R11 post-mortem: permlane32_swap semantics were the R9/R10 bug (A/B-proved);
// shfl_xor path verified. attn 72us; non-attn residual 160us is the target.

#define B_ 2
#define S_ 2048
#define D_ 1024
#define H_ 16
#define HD_ 64
#define NE_ (B_ * S_ * D_)  // 4194304
#define WN_ (D_ * D_)       // 1048576

typedef unsigned short u16;
typedef unsigned int u32;
typedef u16 __attribute__((may_alias)) u16_ma;
typedef float __attribute__((may_alias)) f32_ma;
typedef u32 v4u __attribute__((ext_vector_type(4)));
typedef v4u __attribute__((may_alias)) v4u_ma;
typedef short bf16x8 __attribute__((ext_vector_type(8)));
typedef bf16x8 __attribute__((may_alias)) bf16x8_ma;
typedef float f32x4 __attribute__((ext_vector_type(4)));
typedef float f32x16 __attribute__((ext_vector_type(16)));

__device__ __forceinline__ float bf2f(u16 u) {
  u32 x = ((u32)u) << 16;
  return __builtin_bit_cast(float, x);
}
// Software RNE f32->bf16 (harness-verified numerics, R5-R11).
__device__ __forceinline__ u16 f2bf(float f) {
  __hip_bfloat16 h = __float2bfloat16(f);
  return __builtin_bit_cast(u16, h);
}
// Raw RNE, valid for non-NaN inputs (bit-identical to f2bf there): 3 VALU ops.
__device__ __forceinline__ u16 rne1(float f) {
  u32 a = __builtin_bit_cast(u32, f);
  a += 0x7FFFu + ((a >> 16) & 1u);
  return (u16)(a >> 16);
}
__device__ __forceinline__ u32 rne_pair(float lo, float hi) {
  u32 a = __builtin_bit_cast(u32, lo);
  u32 b = __builtin_bit_cast(u32, hi);
  a += 0x7FFFu + ((a >> 16) & 1u);
  b += 0x7FFFu + ((b >> 16) & 1u);
  return (a >> 16) | (b & 0xFFFF0000u);
}
__device__ __forceinline__ u32 pk2(u32 alo, u32 ahi) {
  return (u32)f2bf(__builtin_bit_cast(float, alo)) |
         ((u32)f2bf(__builtin_bit_cast(float, ahi)) << 16);
}

// async global->LDS, 16B/lane; dest = wave-uniform base + lane*16 (m104).
__device__ __forceinline__ void gl_lds16(const u16* g, u16* l) {
  auto gp = (const __attribute__((address_space(1))) unsigned int*)(const void*)g;
  auto lp = (__attribute__((address_space(3))) unsigned int*)(void*)l;
  __builtin_amdgcn_global_load_lds(gp, lp, 16, 0, 0);
}

// Input dtype detect (R5-R11 harness-verified).
__device__ __forceinline__ bool detect_f32(const u16* Wg) {
  const int lane = threadIdx.x & 63;
  bool hit = false;
#pragma unroll
  for (int i = 0; i < 4; ++i) {
    v4u u = *(const v4u_ma*)(Wg + lane * 32 + i * 8);
#pragma unroll
    for (int j = 0; j < 4; ++j) {
      u32 w = u[j];
      hit |= (((w >> 7) & 0xFFu) >= 0xF0u) || (((w >> 23) & 0xFFu) >= 0xF0u);
    }
  }
  return __any(hit);
}

// ---------------------------------------------------------------------------
// Convert inputs to bf16 scratch — ONLY needed in the fp32 world. bf16 world:
// early-exit (proj reads original d_in directly; bits identical).
// ---------------------------------------------------------------------------
__global__ __launch_bounds__(256) void convert_bf16(
    const void* s0, const void* s1, const void* s2, const void* s3,
    const void* s4, const void* s5, const void* s6, u16* __restrict__ dst_in,
    u16* __restrict__ dst_w, const u16* __restrict__ Wdet) {
  const bool det = detect_f32(Wdet);
  if (!det) return;  // bf16 world: conversion is a no-op copy, skip entirely
  const int y = blockIdx.y;
  const void* src;
  u16* dst;
  int n;
  if (y < 3) {
    src = (y == 0) ? s0 : ((y == 1) ? s1 : s2);
    dst = dst_in + (size_t)y * NE_;
    n = NE_;
  } else {
    src = (y == 3) ? s3 : ((y == 4) ? s4 : ((y == 5) ? s5 : s6));
    dst = dst_w + (size_t)(y - 3) * WN_;
    n = WN_;
  }
  const int i = (blockIdx.x * 256 + threadIdx.x) * 8;
  if (i >= n) return;
  const v4u_ma* fp = (const v4u_ma*)((const float*)src + i);
  v4u f0 = fp[0], f1 = fp[1];
  v4u out;
  out[0] = pk2(f0[0], f0[1]);
  out[1] = pk2(f0[2], f0[3]);
  out[2] = pk2(f1[0], f1[1]);
  out[3] = pk2(f1[2], f1[3]);
  *(v4u_ma*)(dst + i) = out;
}

// ---------------------------------------------------------------------------
// C[4096,1024] = A @ W^T, all-bf16. BM=128, BK=64, BN templated.
// LDS DOUBLE-buffered with counted vmcnt (T4): issue tile kt+1's gl_lds16,
// wait vmcnt(<=LD) so only tile kt's 8 oldest loads must land, barrier,
// compute, barrier. No vmcnt(0) drain mid-loop.
// Source select: det ? converted scratch : original d_in (bit-identical).
// z==0 folds exact 1/sqrt(HD)=0.125 into Q.
// ---------------------------------------------------------------------------
template <int BN, bool OUT_DET>
__global__ __launch_bounds__(256) void proj_g(
    const u16* __restrict__ Asc, const u16* __restrict__ Wsc,
    void* __restrict__ Cb, const u16* __restrict__ Wdet,
    const u16* __restrict__ Ao0, const u16* __restrict__ Ao1,
    const u16* __restrict__ Ao2, const u16* __restrict__ Wo0,
    const u16* __restrict__ Wo1, const u16* __restrict__ Wo2) {
  __shared__ u16 Al[2][128 * 64];
  __shared__ u16 Wl[2][BN * 64];

  const bool det = detect_f32(Wdet);
  const int z = blockIdx.z;

  const u16* Aptr;
  const u16* Wptr;
  if (OUT_DET) {
    Aptr = Asc;  // attn output: always bf16 scratch
    Wptr = det ? Wsc : Wo0;
  } else {
    Aptr = det ? (Asc + (size_t)z * NE_)
               : (z == 0 ? Ao0 : (z == 1 ? Ao1 : Ao2));
    Wptr = det ? (Wsc + (size_t)z * WN_)
               : (z == 0 ? Wo0 : (z == 1 ? Wo1 : Wo2));
  }
  const char* Ag = (const char*)Aptr;
  const char* Wg = (const char*)Wptr;

  const int tid = threadIdx.x;
  const int lane = tid & 63, wid = tid >> 6;
  const int lg = lane >> 4, li = lane & 15;
  const int wr = wid >> 1, wc = wid & 1;
  const int m0 = blockIdx.x * 128, n0 = blockIdx.y * BN;

  const int lr = lane >> 3;
  const int swzb = ((lane & 7) * 16) ^ (lr << 4);

  auto issue = [&](int bi, int kt) {
    const int k0b = kt * 128;  // byte offset along K (64 elems)
#pragma unroll
    for (int c = 0; c < 4; ++c) {
      const int row = wid * 32 + c * 8 + lr;
      gl_lds16((const u16*)(Ag + (size_t)(m0 + row) * 2048 + k0b + swzb),
               &Al[bi][(wid * 32 + c * 8) * 64]);
    }
    if constexpr (BN == 128) {
#pragma unroll
      for (int c = 0; c < 4; ++c) {
        const int row = wid * 32 + c * 8 + lr;
        gl_lds16((const u16*)(Wg + (size_t)(n0 + row) * 2048 + k0b + swzb),
                 &Wl[bi][(wid * 32 + c * 8) * 64]);
      }
    } else {
#pragma unroll
      for (int c = 0; c < 2; ++c) {
        const int row = wid * 16 + c * 8 + lr;
        gl_lds16((const u16*)(Wg + (size_t)(n0 + row) * 2048 + k0b + swzb),
                 &Wl[bi][(wid * 16 + c * 8) * 64]);
      }
    }
  };

  constexpr int NF = BN / 32;
  f32x4 acc[4][NF];
#pragma unroll
  for (int m = 0; m < 4; ++m)
#pragma unroll
    for (int n = 0; n < NF; ++n) acc[m][n] = (f32x4){0.f, 0.f, 0.f, 0.f};

  issue(0, 0);

  for (int kt = 0; kt < 16; ++kt) {
    const int cur = kt & 1;
    if (kt < 15) {
      issue(cur ^ 1, kt + 1);
      // oldest LD loads (tile kt) must land; tile kt+1's may stay in flight
      if constexpr (BN == 128)
        asm volatile("s_waitcnt vmcnt(8)" ::: "memory");
      else
        asm volatile("s_waitcnt vmcnt(6)" ::: "memory");
    } else {
      asm volatile("s_waitcnt vmcnt(0)" ::: "memory");
    }
    __builtin_amdgcn_s_barrier();
    asm volatile("" ::: "memory");  // keep LDS reads below the barrier

#pragma unroll
    for (int ks = 0; ks < 2; ++ks) {
      bf16x8 af[4], bw[NF];
#pragma unroll
      for (int m = 0; m < 4; ++m) {
        const int row = wr * 64 + m * 16 + li;
        af[m] = *(const bf16x8_ma*)((const char*)&Al[cur][0] + row * 128 +
                                    ((ks * 64 + lg * 16) ^ ((row & 7) << 4)));
      }
#pragma unroll
      for (int n = 0; n < NF; ++n) {
        const int row = wc * (BN / 2) + n * 16 + li;
        bw[n] = *(const bf16x8_ma*)((const char*)&Wl[cur][0] + row * 128 +
                                    ((ks * 64 + lg * 16) ^ ((row & 7) << 4)));
      }
#pragma unroll
      for (int m = 0; m < 4; ++m)
#pragma unroll
        for (int n = 0; n < NF; ++n)
          acc[m][n] = __builtin_amdgcn_mfma_f32_16x16x32_bf16(af[m], bw[n],
                                                              acc[m][n], 0, 0, 0);
    }

    asm volatile("" ::: "memory");  // keep LDS reads above the barrier
    __builtin_amdgcn_s_barrier();   // all waves done reading buf[cur] before
                                    // next iter's issue overwrites it
  }

  const bool outf32 = OUT_DET ? det : false;
  // Q (z==0) carries exact 1/sqrt(64) = 0.125 (power of two, no extra error).
  const float zs = (!OUT_DET && z == 0) ? 0.125f : 1.0f;
#pragma unroll
  for (int m = 0; m < 4; ++m)
#pragma unroll
    for (int n = 0; n < NF; ++n)
#pragma unroll
      for (int r = 0; r < 4; ++r) {
        const int row = m0 + wr * 64 + m * 16 + lg * 4 + r;
        const int col = n0 + wc * (BN / 2) + n * 16 + li;
        const size_t idx = (size_t)row * D_ + col;
        const float v = acc[m][n][r] * zs;
        if (OUT_DET) {
          if (outf32)
            ((f32_ma*)Cb)[idx] = v;
          else
            ((u16_ma*)Cb)[idx] = rne1(v);
        } else {
          ((u16_ma*)((u16*)Cb + (size_t)z * NE_))[idx] = rne1(v);
        }
      }
}

// ---------------------------------------------------------------------------
// Flash attention (R11-verified): 32x32x16 MFMA swapped operands,
// shfl_xor(.,32) exchanges, single-barrier K/V dbuf. Only change vs R11:
// raw RNE for P-pack and epilogue (bit-identical on non-NaN).
// ---------------------------------------------------------------------------
__global__ __launch_bounds__(256) void attn3(
    const u16* __restrict__ Qg, const u16* __restrict__ Kg,
    const u16* __restrict__ Vg, u16* __restrict__ Og) {
  __shared__ u16 Kl[2][64 * 64];
  __shared__ u16 VTl[2][64 * 64];

  const int tid = threadIdx.x;
  const int wid = tid >> 6, lane = tid & 63;
  const int l31 = lane & 31;
  const int hi = lane >> 5;

  // T1 XCD swizzle (512 % 8 == 0)
  const int bid = blockIdx.x;
  const int swz = (bid & 7) * 64 + (bid >> 3);
  const int qb = swz & 15;
  const int h = (swz >> 4) & 15;
  const int b = swz >> 8;
  const size_t bbase = (size_t)b * S_ * D_;
  const int hoff = h * HD_;
  const int q0w = qb * 128 + wid * 32;

  // Q B-frags: bq[dblk] -> Q[q0w+l31][hoff + dblk*16 + hi*8 + e]
  bf16x8 bq[4];
  {
    const u16* qp = Qg + bbase + (size_t)(q0w + l31) * D_ + hoff + hi * 8;
#pragma unroll
    for (int dblk = 0; dblk < 4; ++dblk)
      bq[dblk] = *(const bf16x8_ma*)(qp + dblk * 16);
  }

  f32x16 o0, o1;
#pragma unroll
  for (int i = 0; i < 16; ++i) {
    o0[i] = 0.f;
    o1[i] = 0.f;
  }
  float mrun = -1e30f, lrun = 0.f;

  const int krr = tid >> 3;
  const int kc8 = (tid & 7) * 8;
  const int vkr = lane;
  const int vd0 = wid * 8;

  v4u kr0, kr1, vr0, vr1;
  auto kv_load = [&](int kt) {
    const int key0 = kt * 64;
    kr0 = *(const v4u_ma*)(Kg + bbase + (size_t)(key0 + krr) * D_ + hoff + kc8);
    kr1 = *(const v4u_ma*)(Kg + bbase + (size_t)(key0 + 32 + krr) * D_ + hoff + kc8);
    vr0 = *(const v4u_ma*)(Vg + bbase + (size_t)(key0 + vkr) * D_ + hoff + vd0);
    vr1 = *(const v4u_ma*)(Vg + bbase + (size_t)(key0 + vkr) * D_ + hoff + vd0 + 32);
  };
  auto kv_write = [&](int bi) {
    char* Kb = (char*)&Kl[bi][0];
    char* Vb = (char*)&VTl[bi][0];
    const int ksw = (krr & 7) << 4;
    *(v4u_ma*)(Kb + krr * 128 + ((kc8 * 2) ^ ksw)) = kr0;
    *(v4u_ma*)(Kb + (32 + krr) * 128 + ((kc8 * 2) ^ ksw)) = kr1;
    union {
      v4u v;
      u16 e[8];
    } uu;
    uu.v = vr0;
#pragma unroll
    for (int j = 0; j < 8; ++j) {
      const int d = vd0 + j;
      *(u16*)(Vb + d * 128 + ((vkr * 2) ^ ((d & 7) << 4))) = uu.e[j];
    }
    uu.v = vr1;
#pragma unroll
    for (int j = 0; j < 8; ++j) {
      const int d = vd0 + 32 + j;
      *(u16*)(Vb + d * 128 + ((vkr * 2) ^ ((d & 7) << 4))) = uu.e[j];
    }
  };

  kv_load(0);
  kv_write(0);

  const int swk = (l31 & 7) << 4;

  for (int kt = 0; kt < S_ / 64; ++kt) {
    __syncthreads();  // buf[kt&1] writes visible; prior-iter reads all done
    if (kt < S_ / 64 - 1) kv_load(kt + 1);  // in flight across compute

    const char* Kb = (const char*)&Kl[kt & 1][0];
    const char* Vb = (const char*)&VTl[kt & 1][0];

    // QK^T (Q pre-scaled by exact 0.125)
    f32x16 sT0, sT1;
#pragma unroll
    for (int i = 0; i < 16; ++i) {
      sT0[i] = 0.f;
      sT1[i] = 0.f;
    }
    __builtin_amdgcn_s_setprio(1);
#pragma unroll
    for (int dblk = 0; dblk < 4; ++dblk) {
      const int cb = (dblk * 32 + hi * 16);
      bf16x8 a0 = *(const bf16x8_ma*)(Kb + l31 * 128 + (cb ^ swk));
      bf16x8 a1 = *(const bf16x8_ma*)(Kb + (32 + l31) * 128 + (cb ^ swk));
      sT0 = __builtin_amdgcn_mfma_f32_32x32x16_bf16(a0, bq[dblk], sT0, 0, 0, 0);
      sT1 = __builtin_amdgcn_mfma_f32_32x32x16_bf16(a1, bq[dblk], sT1, 0, 0, 0);
    }
    __builtin_amdgcn_s_setprio(0);

    // row max (exact, order-free), cross-half via R8-verified shfl
    float pmax = sT0[0];
#pragma unroll
    for (int i = 0; i < 7; ++i)
      pmax = fmaxf(fmaxf(pmax, sT0[2 * i + 1]), sT0[2 * i + 2]);
    pmax = fmaxf(pmax, sT0[15]);
#pragma unroll
    for (int i = 0; i < 8; ++i)
      pmax = fmaxf(fmaxf(pmax, sT1[2 * i]), sT1[2 * i + 1]);
    pmax = fmaxf(pmax, __shfl_xor(pmax, 32));
    // T13 defer-max (nats, thr 8: P bounded by e^8, R8-verified)
    if (!__all(pmax - mrun <= 8.0f)) {
      const float mnew = fmaxf(mrun, pmax);
      const float al = __expf(mrun - mnew);
      mrun = mnew;
      lrun *= al;
      o0 *= al;
      o1 *= al;
    }

    // p = exp(s - m); raw RNE pack (bit-identical to f2bf: exp never NaN)
    u32 w[16];
    float sum = 0.f;
#pragma unroll
    for (int kh = 0; kh < 2; ++kh)
#pragma unroll
      for (int g = 0; g < 4; ++g)
#pragma unroll
        for (int u = 0; u < 2; ++u) {
          const int r = g * 4 + 2 * u;
          const float pe = __expf((kh ? sT1[r] : sT0[r]) - mrun);
          const float po = __expf((kh ? sT1[r + 1] : sT0[r + 1]) - mrun);
          sum += pe + po;
          w[kh * 8 + g * 2 + u] = rne_pair(pe, po);
        }
    sum += __shfl_xor(sum, 32);
    lrun += sum;

    // P B-frags via R8-VERIFIED shfl pair exchange
    bf16x8 pf[4];
#pragma unroll
    for (int km = 0; km < 4; ++km) {
      const int a = 4 * km;
      const u32 s0 = hi ? w[a] : w[a + 2];
      const u32 s1 = hi ? w[a + 1] : w[a + 3];
      const u32 r0 = (u32)__shfl_xor((int)s0, 32);
      const u32 r1 = (u32)__shfl_xor((int)s1, 32);
      union {
        u32 d[4];
        bf16x8 v;
      } uu;
      uu.d[0] = hi ? r0 : w[a];
      uu.d[1] = hi ? r1 : w[a + 1];
      uu.d[2] = hi ? w[a + 2] : r0;
      uu.d[3] = hi ? w[a + 3] : r1;
      pf[km] = uu.v;
    }

    // PV: O^T += V^T P^T
    __builtin_amdgcn_s_setprio(1);
#pragma unroll
    for (int km = 0; km < 4; ++km) {
      const int cb = (km * 32 + hi * 16);
      bf16x8 v0 = *(const bf16x8_ma*)(Vb + l31 * 128 + (cb ^ swk));
      bf16x8 v1 = *(const bf16x8_ma*)(Vb + (32 + l31) * 128 + (cb ^ swk));
      o0 = __builtin_amdgcn_mfma_f32_32x32x16_bf16(v0, pf[km], o0, 0, 0, 0);
      o1 = __builtin_amdgcn_mfma_f32_32x32x16_bf16(v1, pf[km], o1, 0, 0, 0);
    }
    __builtin_amdgcn_s_setprio(0);

    if (kt < S_ / 64 - 1) kv_write((kt + 1) & 1);
  }

  // epilogue: lane holds O[q=q0w+l31][d=(r&3)+8*(r>>2)+4*hi (+32)]
  const float inv = 1.f / lrun;
  u16* orow = Og + bbase + (size_t)(q0w + l31) * D_ + hoff;
#pragma unroll
  for (int r = 0; r < 16; ++r) {
    const int d0 = (r & 3) + 8 * (r >> 2) + 4 * hi;
    orow[d0] = rne1(o0[r] * inv);
    orow[d0 + 32] = rne1(o1[r] * inv);
  }
}

// ---------------------------------------------------------------------------
// R5 golden slow path — fallback for small-ws worlds.
// ---------------------------------------------------------------------------
template <bool A_SCR, bool SCR_F32, bool OUT_FINAL>
__global__ __launch_bounds__(256) void proj_slow(
    const void* __restrict__ Ag, const u16* __restrict__ Wg,
    void* __restrict__ Cg) {
  const bool det = detect_f32(Wg);
  const bool a_f32 = A_SCR ? SCR_F32 : det;
  const int m = blockIdx.x;
  const int n = blockIdx.y * 256 + threadIdx.x;
  const size_t arow = (size_t)m * D_;
  const size_t wrow = (size_t)n * D_;
  float acc = 0.f;
  for (int k = 0; k < D_; ++k) {
    float a = a_f32 ? ((const f32_ma*)Ag)[arow + k]
                    : bf2f(((const u16_ma*)Ag)[arow + k]);
    float w = det ? ((const f32_ma*)Wg)[wrow + k]
                  : bf2f(((const u16_ma*)Wg)[wrow + k]);
    acc += a * w;
  }
  const size_t ci = (size_t)m * D_ + n;
  const bool c_f32 = OUT_FINAL ? det : SCR_F32;
  if (c_f32)
    ((f32_ma*)Cg)[ci] = acc;
  else
    ((u16_ma*)Cg)[ci] = f2bf(acc);
}

template <bool SCR_F32>
__global__ __launch_bounds__(256) void attn_slow(
    const void* __restrict__ Qg, const void* __restrict__ Kg,
    const void* __restrict__ Vg, void* __restrict__ Cg) {
  const int tid = threadIdx.x;
  const int qblk = blockIdx.x & 7;
  const int h = (blockIdx.x >> 3) & 15;
  const int b = blockIdx.x >> 7;
  const int q = qblk * 256 + tid;
  const size_t base = (size_t)b * S_ * D_;
  const int hoff = h * HD_;
  float qv[64];
  {
    const size_t qrow = base + (size_t)q * D_ + hoff;
    for (int d = 0; d < 64; ++d)
      qv[d] = SCR_F32 ? ((const f32_ma*)Qg)[qrow + d]
                      : bf2f(((const u16_ma*)Qg)[qrow + d]);
  }
  float o[64];
  for (int d = 0; d < 64; ++d) o[d] = 0.f;
  float m = -1e30f, l = 0.f;
  for (int key = 0; key < S_; ++key) {
    const size_t krow = base + (size_t)key * D_ + hoff;
    float s = 0.f;
    for (int d = 0; d < 64; ++d) {
      float kx = SCR_F32 ? ((const f32_ma*)Kg)[krow + d]
                         : bf2f(((const u16_ma*)Kg)[krow + d]);
      s += qv[d] * kx;
    }
    s *= 0.125f;
    float mn = fmaxf(m, s);
    float al = expf(m - mn);
    float pe = expf(s - mn);
    m = mn;
    l = l * al + pe;
    for (int d = 0; d < 64; ++d) {
      float vx = SCR_F32 ? ((const f32_ma*)Vg)[krow + d]
                         : bf2f(((const u16_ma*)Vg)[krow + d]);
      o[d] = o[d] * al + pe * vx;
    }
  }
  const float il = 1.f / l;
  const size_t crow = base + (size_t)q * D_ + hoff;
  for (int d = 0; d < 64; ++d) {
    if (SCR_F32)
      ((f32_ma*)Cg)[crow + d] = o[d] * il;
    else
      ((u16_ma*)Cg)[crow + d] = f2bf(o[d] * il);
  }
}

extern "C" void kernel_launch(void* const* d_in, const int* in_sizes, int n_in,
                              void* d_out, int out_size, void* d_ws,
                              size_t ws_size, hipStream_t stream) {
  const u16* Wdet = (const u16*)d_in[3];  // pristine Wq for dtype detect
  dim3 blk(256);

  if (ws_size >= (size_t)4 * NE_ * sizeof(float)) {
    u16* Qi = (u16*)d_ws;
    u16* Wc = Qi + (size_t)3 * NE_;
    u16* Qp = Wc + (size_t)4 * WN_;
    u16* Xp = Qp + (size_t)3 * NE_;

    convert_bf16<<<dim3(2048, 7), blk, 0, stream>>>(
        d_in[0], d_in[1], d_in[2], d_in[3], d_in[4], d_in[5], d_in[6], Qi, Wc,
        Wdet);
    proj_g<128, false><<<dim3(32, 8, 3), blk, 0, stream>>>(
        Qi, Wc, Qp, Wdet, (const u16*)d_in[0], (const u16*)d_in[1],
        (const u16*)d_in[2], (const u16*)d_in[3], (const u16*)d_in[4],
        (const u16*)d_in[5]);
    attn3<<<dim3(512), blk, 0, stream>>>(Qp, Qp + NE_, Qp + (size_t)2 * NE_, Xp);
    proj_g<64, true><<<dim3(32, 16, 1), blk, 0, stream>>>(
        Xp, Wc + (size_t)3 * WN_, d_out, Wdet, nullptr, nullptr, nullptr,
        (const u16*)d_in[6], nullptr, nullptr);
  } else {
    dim3 gproj(B_ * S_, D_ / 256);
    dim3 gattn(B_ * H_ * (S_ / 256));
    u16* Qp = (u16*)d_out;
    u16* Kp = (u16*)d_in[0];
    u16* Vp = (u16*)d_in[1];
    u16* Xp = (u16*)d_in[2];
    proj_slow<false, false, false><<<gproj, blk, 0, stream>>>(
        d_in[0], (const u16*)d_in[3], Qp);
    proj_slow<false, false, false><<<gproj, blk, 0, stream>>>(
        d_in[1], (const u16*)d_in[4], Kp);
    proj_slow<false, false, false><<<gproj, blk, 0, stream>>>(
        d_in[2], (const u16*)d_in[5], Vp);
    attn_slow<false><<<gattn, blk, 0, stream>>>(Qp, Kp, Vp, Xp);
    proj_slow<true, false, true><<<gproj, blk, 0, stream>>>(
        Xp, (const u16*)d_in[6], d_out);
  }
}